// Round 1
// baseline (665.658 us; speedup 1.0000x reference)
//
#include <hip/hip_runtime.h>
#include <hip/hip_bf16.h>
#include <stdint.h>

#define M_DIM 8192
#define N_DIM 4096
#define K_DIM 4096
#define BM 128
#define BN 128
#define BK 32

typedef float f32x4 __attribute__((ext_vector_type(4)));
typedef __bf16 bf16x8 __attribute__((ext_vector_type(8)));
typedef short s16x8 __attribute__((ext_vector_type(8)));

// MFMA dispatch: prefer native __bf16 operand signature (clang V8y); SFINAE
// fallback to short8 in case this ROCm build uses the i16-vector signature.
template <typename AB>
__device__ __forceinline__ auto mfma_16x16x32(AB a, AB b, f32x4 c, int)
    -> decltype(__builtin_amdgcn_mfma_f32_16x16x32_bf16(a, b, c, 0, 0, 0)) {
  return __builtin_amdgcn_mfma_f32_16x16x32_bf16(a, b, c, 0, 0, 0);
}
template <typename AB>
__device__ __forceinline__ f32x4 mfma_16x16x32(AB a, AB b, f32x4 c, long) {
  return __builtin_amdgcn_mfma_f32_16x16x32_bf16(
      __builtin_bit_cast(s16x8, a), __builtin_bit_cast(s16x8, b), c, 0, 0, 0);
}

__device__ __forceinline__ uint16_t f2b(float f) {
  union { float f; uint32_t u; } v; v.f = f;
  uint32_t u = v.u;
  u += 0x7FFFu + ((u >> 16) & 1u);   // round-to-nearest-even
  return (uint16_t)(u >> 16);
}

__device__ __forceinline__ void load16_lds(const uint16_t* g, uint16_t* l) {
  __builtin_amdgcn_global_load_lds(
      (__attribute__((address_space(1))) void*)(void*)g,
      (__attribute__((address_space(3))) void*)l, 16, 0, 0);
}

// ---- fp32 -> bf16 convert for activations: 8 elems/thread ----
__global__ void cvt_f32_to_bf16(const float* __restrict__ in, uint16_t* __restrict__ out) {
  size_t t = (size_t)blockIdx.x * blockDim.x + threadIdx.x;
  const float4* p = (const float4*)in + t * 2;
  float4 a = p[0];
  float4 b = p[1];
  uint4 o;
  o.x = (uint32_t)f2b(a.x) | ((uint32_t)f2b(a.y) << 16);
  o.y = (uint32_t)f2b(a.z) | ((uint32_t)f2b(a.w) << 16);
  o.z = (uint32_t)f2b(b.x) | ((uint32_t)f2b(b.y) << 16);
  o.w = (uint32_t)f2b(b.z) | ((uint32_t)f2b(b.w) << 16);
  ((uint4*)out)[t] = o;
}

// ---- NF4 dequant: weight fp32 -> qweight bf16, 8 elems/thread (one group-slice) ----
__global__ void dequant_nf4(const float* __restrict__ w, const float* __restrict__ scales,
                            const float* __restrict__ values, const float* __restrict__ pivots,
                            uint16_t* __restrict__ out) {
  __shared__ float sv[16];
  if (threadIdx.x < 16) sv[threadIdx.x] = values[threadIdx.x];
  float pv[15];
#pragma unroll
  for (int j = 0; j < 15; ++j) pv[j] = pivots[j];   // uniform -> SGPRs
  __syncthreads();
  size_t t = (size_t)blockIdx.x * blockDim.x + threadIdx.x;
  size_t base = t * 8;                 // 8 | 64 -> single group per thread-slice
  float scale = scales[base >> 6];
  const float4* p = (const float4*)(w + base);
  float4 a = p[0], b = p[1];
  float e[8] = {a.x, a.y, a.z, a.w, b.x, b.y, b.z, b.w};
  uint32_t words[4];
#pragma unroll
  for (int i = 0; i < 4; ++i) {
    uint32_t half_w[2];
#pragma unroll
    for (int h = 0; h < 2; ++h) {
      float s = fminf(fmaxf(e[2 * i + h] / scale, -1.0f), 1.0f);  // exact fp32 div, like np
      int idx = 0;
#pragma unroll
      for (int j = 0; j < 15; ++j) idx += (pv[j] < s) ? 1 : 0;    // searchsorted side='left'
      half_w[h] = f2b(sv[idx] * scale);
    }
    words[i] = half_w[0] | (half_w[1] << 16);
  }
  uint4 o = {words[0], words[1], words[2], words[3]};
  ((uint4*)out)[t] = o;
}

// ---- bf16 GEMM, C[m,n] = sum_k A[m,k]*B[n,k]; A[M,K], B[N,K] row-major ----
__global__ __launch_bounds__(256) void gemm_bt(const uint16_t* __restrict__ A,
                                               const uint16_t* __restrict__ B,
                                               float* __restrict__ C) {
  __shared__ uint16_t As[BM * BK];   // no padding: global_load_lds lane-contiguous layout
  __shared__ uint16_t Bs[BN * BK];
  const int tid = threadIdx.x;
  const int wave = tid >> 6;
  const int lane = tid & 63;
  const int bm = blockIdx.y;
  const int bn = blockIdx.x;

  // staging: each lane loads 16B; wave covers 16 rows x 32 cols per issue, 2 issues each for A/B
  const int srow = wave * 16 + (lane >> 2);
  const int scol = (lane & 3) * 8;
  const uint16_t* ag0 = A + (size_t)(bm * BM + srow) * K_DIM + scol;
  const uint16_t* ag1 = ag0 + (size_t)64 * K_DIM;
  const uint16_t* bg0 = B + (size_t)(bn * BN + srow) * K_DIM + scol;
  const uint16_t* bg1 = bg0 + (size_t)64 * K_DIM;
  uint16_t* al0 = &As[(wave * 16) * BK];
  uint16_t* al1 = &As[(64 + wave * 16) * BK];
  uint16_t* bl0 = &Bs[(wave * 16) * BK];
  uint16_t* bl1 = &Bs[(64 + wave * 16) * BK];

  // wave tile: 64x64; 4x4 subtiles of 16x16x32 MFMA
  const int wm = (wave >> 1) * 64;
  const int wn = (wave & 1) * 64;
  const int fr = lane & 15;     // A row / B row (=C col) within subtile
  const int fq = lane >> 4;     // k-quad
  const uint16_t* As_rd = &As[(wm + fr) * BK + fq * 8];
  const uint16_t* Bs_rd = &Bs[(wn + fr) * BK + fq * 8];

  f32x4 acc[4][4] = {};

  for (int k0 = 0; k0 < K_DIM; k0 += BK) {
    load16_lds(ag0 + k0, al0);
    load16_lds(ag1 + k0, al1);
    load16_lds(bg0 + k0, bl0);
    load16_lds(bg1 + k0, bl1);
    __syncthreads();   // waits vmcnt(0): staging visible
    bf16x8 af[4], bf[4];
#pragma unroll
    for (int i = 0; i < 4; ++i) af[i] = *(const bf16x8*)(As_rd + i * 16 * BK);
#pragma unroll
    for (int j = 0; j < 4; ++j) bf[j] = *(const bf16x8*)(Bs_rd + j * 16 * BK);
#pragma unroll
    for (int i = 0; i < 4; ++i)
#pragma unroll
      for (int j = 0; j < 4; ++j)
        acc[i][j] = mfma_16x16x32(af[i], bf[j], acc[i][j], 0);
    __syncthreads();   // protect LDS before next overwrite
  }

  // epilogue: C/D layout col=lane&15, row=(lane>>4)*4+reg
  float* crow = C + (size_t)(bm * BM + wm + fq * 4) * N_DIM + (bn * BN + wn + fr);
#pragma unroll
  for (int i = 0; i < 4; ++i)
#pragma unroll
    for (int j = 0; j < 4; ++j)
#pragma unroll
      for (int r = 0; r < 4; ++r)
        crow[(size_t)(i * 16 + r) * N_DIM + j * 16] = acc[i][j][r];
}

extern "C" void kernel_launch(void* const* d_in, const int* in_sizes, int n_in,
                              void* d_out, int out_size, void* d_ws, size_t ws_size,
                              hipStream_t stream) {
  const float* inp    = (const float*)d_in[0];  // [4,2048,4096]
  const float* weight = (const float*)d_in[1];  // [4096,4096]
  const float* scales = (const float*)d_in[2];  // [262144,1]
  const float* values = (const float*)d_in[3];  // [16]
  const float* pivots = (const float*)d_in[4];  // [15]
  float* out = (float*)d_out;                   // [4,2048,4096] fp32

  uint16_t* A_bf16 = (uint16_t*)d_ws;                   // 8192*4096 bf16 = 64 MiB
  uint16_t* B_bf16 = A_bf16 + (size_t)M_DIM * K_DIM;    // 4096*4096 bf16 = 32 MiB

  cvt_f32_to_bf16<<<(M_DIM * (size_t)K_DIM / 8) / 256, 256, 0, stream>>>(inp, A_bf16);
  dequant_nf4<<<(N_DIM * (size_t)K_DIM / 8) / 256, 256, 0, stream>>>(weight, scales, values,
                                                                     pivots, B_bf16);
  dim3 grid(N_DIM / BN, M_DIM / BM);  // (32, 64)
  gemm_bt<<<grid, 256, 0, stream>>>(A_bf16, B_bf16, out);
}

// Round 2
// 576.852 us; speedup vs baseline: 1.1540x; 1.1540x over previous
//
#include <hip/hip_runtime.h>
#include <hip/hip_bf16.h>
#include <stdint.h>

#define M_DIM 8192
#define N_DIM 4096
#define K_DIM 4096
#define BM 128
#define BN 128
#define BK 64

typedef float f32x4 __attribute__((ext_vector_type(4)));
typedef __bf16 bf16x8 __attribute__((ext_vector_type(8)));
typedef short s16x8 __attribute__((ext_vector_type(8)));

// MFMA dispatch: prefer native __bf16 operand signature; fallback to short8.
template <typename AB>
__device__ __forceinline__ auto mfma_16x16x32(AB a, AB b, f32x4 c, int)
    -> decltype(__builtin_amdgcn_mfma_f32_16x16x32_bf16(a, b, c, 0, 0, 0)) {
  return __builtin_amdgcn_mfma_f32_16x16x32_bf16(a, b, c, 0, 0, 0);
}
template <typename AB>
__device__ __forceinline__ f32x4 mfma_16x16x32(AB a, AB b, f32x4 c, long) {
  return __builtin_amdgcn_mfma_f32_16x16x32_bf16(
      __builtin_bit_cast(s16x8, a), __builtin_bit_cast(s16x8, b), c, 0, 0, 0);
}

__device__ __forceinline__ uint16_t f2b(float f) {
  union { float f; uint32_t u; } v; v.f = f;
  uint32_t u = v.u;
  u += 0x7FFFu + ((u >> 16) & 1u);   // round-to-nearest-even
  return (uint16_t)(u >> 16);
}

__device__ __forceinline__ void load16_lds(const uint16_t* g, uint16_t* l) {
  __builtin_amdgcn_global_load_lds(
      (__attribute__((address_space(1))) void*)(void*)g,
      (__attribute__((address_space(3))) void*)l, 16, 0, 0);
}

// ---- fp32 -> bf16 convert for activations: 8 elems/thread ----
__global__ void cvt_f32_to_bf16(const float* __restrict__ in, uint16_t* __restrict__ out) {
  size_t t = (size_t)blockIdx.x * blockDim.x + threadIdx.x;
  const float4* p = (const float4*)in + t * 2;
  float4 a = p[0];
  float4 b = p[1];
  uint4 o;
  o.x = (uint32_t)f2b(a.x) | ((uint32_t)f2b(a.y) << 16);
  o.y = (uint32_t)f2b(a.z) | ((uint32_t)f2b(a.w) << 16);
  o.z = (uint32_t)f2b(b.x) | ((uint32_t)f2b(b.y) << 16);
  o.w = (uint32_t)f2b(b.z) | ((uint32_t)f2b(b.w) << 16);
  ((uint4*)out)[t] = o;
}

// ---- NF4 dequant: weight fp32 -> qweight bf16, 8 elems/thread ----
__global__ void dequant_nf4(const float* __restrict__ w, const float* __restrict__ scales,
                            const float* __restrict__ values, const float* __restrict__ pivots,
                            uint16_t* __restrict__ out) {
  __shared__ float sv[16];
  if (threadIdx.x < 16) sv[threadIdx.x] = values[threadIdx.x];
  float pv[15];
#pragma unroll
  for (int j = 0; j < 15; ++j) pv[j] = pivots[j];   // uniform -> SGPRs
  __syncthreads();
  size_t t = (size_t)blockIdx.x * blockDim.x + threadIdx.x;
  size_t base = t * 8;                 // 8 | 64 -> single group per thread-slice
  float scale = scales[base >> 6];
  const float4* p = (const float4*)(w + base);
  float4 a = p[0], b = p[1];
  float e[8] = {a.x, a.y, a.z, a.w, b.x, b.y, b.z, b.w};
  uint32_t words[4];
#pragma unroll
  for (int i = 0; i < 4; ++i) {
    uint32_t half_w[2];
#pragma unroll
    for (int h = 0; h < 2; ++h) {
      float s = fminf(fmaxf(e[2 * i + h] / scale, -1.0f), 1.0f);  // exact fp32 div, like np
      int idx = 0;
#pragma unroll
      for (int j = 0; j < 15; ++j) idx += (pv[j] < s) ? 1 : 0;    // searchsorted side='left'
      half_w[h] = f2b(sv[idx] * scale);
    }
    words[i] = half_w[0] | (half_w[1] << 16);
  }
  uint4 o = {words[0], words[1], words[2], words[3]};
  ((uint4*)out)[t] = o;
}

// ---- bf16 GEMM, C[m,n] = sum_k A[m,k]*B[n,k]; A[M,K], B[N,K] row-major ----
// BK=64: staging windows are full 128 B cache lines. LDS rows are 8 chunks of
// 16 B; chunk c of row r lives at slot c ^ (r&7) (XOR swizzle) -> ds_read_b128
// is conflict-free per 8-lane phase. global_load_lds dest stays lane-contiguous;
// the swizzle is applied by permuting each lane's *source* chunk.
__global__ __launch_bounds__(256) void gemm_bt(const uint16_t* __restrict__ A,
                                               const uint16_t* __restrict__ B,
                                               float* __restrict__ C) {
  __shared__ uint16_t As[BM * BK];   // 16 KiB
  __shared__ uint16_t Bs[BN * BK];   // 16 KiB
  const int tid = threadIdx.x;
  const int wave = tid >> 6;
  const int lane = tid & 63;
  const int bm = blockIdx.y;
  const int bn = blockIdx.x;

  // staging: per issue a wave covers 8 rows x 128 B; each wave does 4 issues
  // for A (rows wave*32..+31) and 4 for B.
  const int lr = lane >> 3;                 // row within issue (0..7)
  const int lc = (lane & 7) ^ lr;           // swizzled source chunk (8 elems)
  const uint16_t* ag[4];
  const uint16_t* bg[4];
  uint16_t* al[4];
  uint16_t* bl[4];
#pragma unroll
  for (int i = 0; i < 4; ++i) {
    int row = wave * 32 + i * 8 + lr;       // row&7 == lr (bases are mult of 8)
    ag[i] = A + (size_t)(bm * BM + row) * K_DIM + lc * 8;
    bg[i] = B + (size_t)(bn * BN + row) * K_DIM + lc * 8;
    al[i] = &As[(wave * 32 + i * 8) * BK];
    bl[i] = &Bs[(wave * 32 + i * 8) * BK];
  }

  // wave tile: 64x64; 4x4 subtiles of 16x16x32 MFMA
  const int wm = (wave >> 1) * 64;
  const int wn = (wave & 1) * 64;
  const int fr = lane & 15;     // row within subtile
  const int fq = lane >> 4;     // k-quad (8 elems each)

  f32x4 acc[4][4] = {};

  for (int k0 = 0; k0 < K_DIM; k0 += BK) {
#pragma unroll
    for (int i = 0; i < 4; ++i) load16_lds(ag[i] + k0, al[i]);
#pragma unroll
    for (int i = 0; i < 4; ++i) load16_lds(bg[i] + k0, bl[i]);
    __syncthreads();
#pragma unroll
    for (int ks = 0; ks < 2; ++ks) {
      const int csl = ((ks * 4 + fq) ^ (fr & 7)) * 8;   // swizzled chunk slot
      bf16x8 af[4], bf[4];
#pragma unroll
      for (int i = 0; i < 4; ++i) af[i] = *(const bf16x8*)&As[(wm + i * 16 + fr) * BK + csl];
#pragma unroll
      for (int j = 0; j < 4; ++j) bf[j] = *(const bf16x8*)&Bs[(wn + j * 16 + fr) * BK + csl];
#pragma unroll
      for (int i = 0; i < 4; ++i)
#pragma unroll
        for (int j = 0; j < 4; ++j)
          acc[i][j] = mfma_16x16x32(af[i], bf[j], acc[i][j], 0);
    }
    __syncthreads();
  }

  // epilogue: C/D layout col=lane&15, row=(lane>>4)*4+reg
  float* crow = C + (size_t)(bm * BM + wm + fq * 4) * N_DIM + (bn * BN + wn + fr);
#pragma unroll
  for (int i = 0; i < 4; ++i)
#pragma unroll
    for (int j = 0; j < 4; ++j)
#pragma unroll
      for (int r = 0; r < 4; ++r)
        crow[(size_t)(i * 16 + r) * N_DIM + j * 16] = acc[i][j][r];
}

extern "C" void kernel_launch(void* const* d_in, const int* in_sizes, int n_in,
                              void* d_out, int out_size, void* d_ws, size_t ws_size,
                              hipStream_t stream) {
  const float* inp    = (const float*)d_in[0];  // [4,2048,4096]
  const float* weight = (const float*)d_in[1];  // [4096,4096]
  const float* scales = (const float*)d_in[2];  // [262144,1]
  const float* values = (const float*)d_in[3];  // [16]
  const float* pivots = (const float*)d_in[4];  // [15]
  float* out = (float*)d_out;                   // [4,2048,4096] fp32

  uint16_t* A_bf16 = (uint16_t*)d_ws;                   // 8192*4096 bf16 = 64 MiB
  uint16_t* B_bf16 = A_bf16 + (size_t)M_DIM * K_DIM;    // 4096*4096 bf16 = 32 MiB

  cvt_f32_to_bf16<<<(M_DIM * (size_t)K_DIM / 8) / 256, 256, 0, stream>>>(inp, A_bf16);
  dequant_nf4<<<(N_DIM * (size_t)K_DIM / 8) / 256, 256, 0, stream>>>(weight, scales, values,
                                                                     pivots, B_bf16);
  dim3 grid(N_DIM / BN, M_DIM / BM);  // (32, 64)
  gemm_bt<<<grid, 256, 0, stream>>>(A_bf16, B_bf16, out);
}

// Round 3
// 552.775 us; speedup vs baseline: 1.2042x; 1.0436x over previous
//
#include <hip/hip_runtime.h>
#include <hip/hip_bf16.h>
#include <stdint.h>

#define M_DIM 8192
#define N_DIM 4096
#define K_DIM 4096
#define BM 128
#define BN 128
#define BK 64

#define CVT_BLOCKS 8192   // 33.5M elems / 16 per thread / 256
#define DQ_BLOCKS  8192   // 16.8M elems /  8 per thread / 256

typedef float f32x4 __attribute__((ext_vector_type(4)));
typedef float f32x16 __attribute__((ext_vector_type(16)));
typedef __bf16 bf16x8 __attribute__((ext_vector_type(8)));
typedef short s16x8 __attribute__((ext_vector_type(8)));

// MFMA dispatch: prefer native __bf16 operand signature; fallback to short8.
template <typename AB>
__device__ __forceinline__ auto mfma_32x32x16(AB a, AB b, f32x16 c, int)
    -> decltype(__builtin_amdgcn_mfma_f32_32x32x16_bf16(a, b, c, 0, 0, 0)) {
  return __builtin_amdgcn_mfma_f32_32x32x16_bf16(a, b, c, 0, 0, 0);
}
template <typename AB>
__device__ __forceinline__ f32x16 mfma_32x32x16(AB a, AB b, f32x16 c, long) {
  return __builtin_amdgcn_mfma_f32_32x32x16_bf16(
      __builtin_bit_cast(s16x8, a), __builtin_bit_cast(s16x8, b), c, 0, 0, 0);
}

__device__ __forceinline__ uint16_t f2b(float f) {
  union { float f; uint32_t u; } v; v.f = f;
  uint32_t u = v.u;
  u += 0x7FFFu + ((u >> 16) & 1u);   // round-to-nearest-even
  return (uint16_t)(u >> 16);
}

__device__ __forceinline__ void load16_lds(const uint16_t* g, uint16_t* l) {
  __builtin_amdgcn_global_load_lds(
      (__attribute__((address_space(1))) void*)(void*)g,
      (__attribute__((address_space(3))) void*)l, 16, 0, 0);
}

// ---- fused pre-pass: blocks [0,CVT_BLOCKS) convert inp fp32->bf16 (16/thr);
//      blocks [CVT_BLOCKS, ..) dequant NF4 weight -> bf16 (8/thr, div-free) ----
__global__ __launch_bounds__(256) void prep(const float* __restrict__ inp,
                                            uint16_t* __restrict__ A_bf16,
                                            const float* __restrict__ w,
                                            const float* __restrict__ scales,
                                            const float* __restrict__ values,
                                            const float* __restrict__ pivots,
                                            uint16_t* __restrict__ B_bf16) {
  if (blockIdx.x < CVT_BLOCKS) {
    size_t t = (size_t)blockIdx.x * blockDim.x + threadIdx.x;
    const float4* p = (const float4*)inp + t * 4;
    uint4* q = (uint4*)A_bf16 + t * 2;
#pragma unroll
    for (int h = 0; h < 2; ++h) {
      float4 a = p[2 * h], b = p[2 * h + 1];
      uint4 o;
      o.x = (uint32_t)f2b(a.x) | ((uint32_t)f2b(a.y) << 16);
      o.y = (uint32_t)f2b(a.z) | ((uint32_t)f2b(a.w) << 16);
      o.z = (uint32_t)f2b(b.x) | ((uint32_t)f2b(b.y) << 16);
      o.w = (uint32_t)f2b(b.z) | ((uint32_t)f2b(b.w) << 16);
      q[h] = o;
    }
  } else {
    __shared__ float sv[16];
    if (threadIdx.x < 16) sv[threadIdx.x] = values[threadIdx.x];
    float pv[15];
#pragma unroll
    for (int j = 0; j < 15; ++j) pv[j] = pivots[j];   // uniform -> SGPRs
    __syncthreads();
    size_t t = (size_t)(blockIdx.x - CVT_BLOCKS) * blockDim.x + threadIdx.x;
    size_t base = t * 8;
    float scale = scales[base >> 6];
    // pv[j] < w/scale  <=>  pv[j]*scale < w  (scale > 0); clip redundant
    float psc[15];
#pragma unroll
    for (int j = 0; j < 15; ++j) psc[j] = pv[j] * scale;
    const float4* p = (const float4*)(w + base);
    float4 a = p[0], b = p[1];
    float e[8] = {a.x, a.y, a.z, a.w, b.x, b.y, b.z, b.w};
    uint32_t words[4];
#pragma unroll
    for (int i = 0; i < 4; ++i) {
      uint32_t hw[2];
#pragma unroll
      for (int h = 0; h < 2; ++h) {
        float x = e[2 * i + h];
        int idx = 0;
#pragma unroll
        for (int j = 0; j < 15; ++j) idx += (psc[j] < x) ? 1 : 0;  // searchsorted left
        hw[h] = f2b(sv[idx] * scale);   // 16-word table: broadcast, conflict-free
      }
      words[i] = hw[0] | (hw[1] << 16);
    }
    uint4 o = {words[0], words[1], words[2], words[3]};
    ((uint4*)B_bf16)[t] = o;
  }
}

// ---- bf16 GEMM, C[m,n] = sum_k A[m,k]*B[n,k]; 32x32x16 MFMA, XOR-swizzled LDS ----
__global__ __launch_bounds__(256) void gemm_bt(const uint16_t* __restrict__ A,
                                               const uint16_t* __restrict__ B,
                                               float* __restrict__ C) {
  __shared__ uint16_t As[BM * BK];   // 16 KiB
  __shared__ uint16_t Bs[BN * BK];   // 16 KiB
  const int tid = threadIdx.x;
  const int wave = tid >> 6;
  const int lane = tid & 63;
  const int bm = blockIdx.y;
  const int bn = blockIdx.x;

  // staging: per issue a wave covers 8 rows x 128 B; chunk c of row r at slot c^(r&7)
  const int lr = lane >> 3;
  const int lc = (lane & 7) ^ lr;
  const uint16_t* ag[4];
  const uint16_t* bg[4];
  uint16_t* al[4];
  uint16_t* bl[4];
#pragma unroll
  for (int i = 0; i < 4; ++i) {
    int row = wave * 32 + i * 8 + lr;
    ag[i] = A + (size_t)(bm * BM + row) * K_DIM + lc * 8;
    bg[i] = B + (size_t)(bn * BN + row) * K_DIM + lc * 8;
    al[i] = &As[(wave * 32 + i * 8) * BK];
    bl[i] = &Bs[(wave * 32 + i * 8) * BK];
  }

  // wave tile 64x64 = 2x2 subtiles of 32x32; frag: m=lane&31, k=(lane>>5)*8+j
  const int wm = (wave >> 1) * 64;
  const int wn = (wave & 1) * 64;
  const int r31 = lane & 31;
  const int kh = lane >> 5;

  f32x16 acc[2][2] = {};

  for (int k0 = 0; k0 < K_DIM; k0 += BK) {
#pragma unroll
    for (int i = 0; i < 4; ++i) load16_lds(ag[i] + k0, al[i]);
#pragma unroll
    for (int i = 0; i < 4; ++i) load16_lds(bg[i] + k0, bl[i]);
    __syncthreads();
#pragma unroll
    for (int ks = 0; ks < 4; ++ks) {
      const int csl = ((ks * 2 + kh) ^ (r31 & 7)) * 8;   // swizzled chunk slot
      bf16x8 af[2], bf[2];
#pragma unroll
      for (int i = 0; i < 2; ++i) af[i] = *(const bf16x8*)&As[(wm + i * 32 + r31) * BK + csl];
#pragma unroll
      for (int j = 0; j < 2; ++j) bf[j] = *(const bf16x8*)&Bs[(wn + j * 32 + r31) * BK + csl];
#pragma unroll
      for (int i = 0; i < 2; ++i)
#pragma unroll
        for (int j = 0; j < 2; ++j)
          acc[i][j] = mfma_32x32x16(af[i], bf[j], acc[i][j], 0);
    }
    __syncthreads();
  }

  // epilogue: C/D 32x32: col=lane&31, row=(reg&3)+8*(reg>>2)+4*(lane>>5)
  const int crow0 = bm * BM + wm;
  const int ccol0 = bn * BN + wn + r31;
#pragma unroll
  for (int i = 0; i < 2; ++i)
#pragma unroll
    for (int j = 0; j < 2; ++j)
#pragma unroll
      for (int reg = 0; reg < 16; ++reg) {
        int row = i * 32 + (reg & 3) + 8 * (reg >> 2) + 4 * kh;
        C[(size_t)(crow0 + row) * N_DIM + ccol0 + j * 32] = acc[i][j][reg];
      }
}

extern "C" void kernel_launch(void* const* d_in, const int* in_sizes, int n_in,
                              void* d_out, int out_size, void* d_ws, size_t ws_size,
                              hipStream_t stream) {
  const float* inp    = (const float*)d_in[0];  // [4,2048,4096]
  const float* weight = (const float*)d_in[1];  // [4096,4096]
  const float* scales = (const float*)d_in[2];  // [262144,1]
  const float* values = (const float*)d_in[3];  // [16]
  const float* pivots = (const float*)d_in[4];  // [15]
  float* out = (float*)d_out;                   // [4,2048,4096] fp32

  uint16_t* A_bf16 = (uint16_t*)d_ws;                   // 8192*4096 bf16 = 64 MiB
  uint16_t* B_bf16 = A_bf16 + (size_t)M_DIM * K_DIM;    // 4096*4096 bf16 = 32 MiB

  prep<<<CVT_BLOCKS + DQ_BLOCKS, 256, 0, stream>>>(inp, A_bf16, weight, scales, values,
                                                   pivots, B_bf16);
  dim3 grid(N_DIM / BN, M_DIM / BM);  // (32, 64)
  gemm_bt<<<grid, 256, 0, stream>>>(A_bf16, B_bf16, out);
}